// Round 1
// baseline (935.083 us; speedup 1.0000x reference)
//
#include <hip/hip_runtime.h>
#include <hip/hip_bf16.h>
#include <math.h>

// Problem constants
#define BB 8
#define DD 4096
#define SS 16
#define NHH 32
#define FFF 16384
#define DPH 128           // DD/NHH
#define D3 12288          // 3*DD

// ---------------- workspace layout (floats) ----------------
// zeroed region first (single memset):
//   z    [B][3D]   @ 0          (98304)
//   xw   [B][D]    @ 98304      (32768)
//   a1   [B][FF]   @ 131072     (131072)
//   a3   [B][FF]   @ 262144     (131072)
//   xd   [B][D]    @ 393216     (32768)
// non-zeroed:
//   xn1  [B][D]    @ 425984
//   y    [B][D]    @ 458752
//   xattn[B][D]    @ 491520
//   xn2  [B][D]    @ 524288
//   g    [B][FF]   @ 557056
#define WS_Z     0
#define WS_XW    98304
#define WS_A1    131072
#define WS_A3    262144
#define WS_XD    393216
#define WS_ZERO_COUNT 425984
#define WS_XN1   425984
#define WS_Y     458752
#define WS_XATTN 491520
#define WS_XN2   524288
#define WS_G     557056

// ---------------- rmsnorm (pre) ----------------
__global__ __launch_bounds__(256) void rmsnorm1_k(const float* __restrict__ x,
                                                  const float* __restrict__ w,
                                                  float* __restrict__ xn) {
    const int b = blockIdx.x;
    const int tid = threadIdx.x;
    float ss = 0.f;
    for (int d = tid; d < DD; d += 256) { float v = x[b*DD + d]; ss += v*v; }
    __shared__ float red[4];
    #pragma unroll
    for (int o = 32; o > 0; o >>= 1) ss += __shfl_down(ss, o);
    if ((tid & 63) == 0) red[tid >> 6] = ss;
    __syncthreads();
    float total = red[0] + red[1] + red[2] + red[3];
    float scale = rsqrtf(total / (float)DD + 1e-6f);
    for (int d = tid; d < DD; d += 256) xn[b*DD + d] = x[b*DD + d] * scale * w[d];
}

// ---------------- batch-8 GEMV, split-K via atomics ----------------
// W is [N][M] row-major; out[b][M] accumulated atomically (pre-zeroed).
// grid.x = M/512 column tiles, grid.y = N/RPB row chunks. 256 threads.
template<int RPB, int M>
__global__ __launch_bounds__(256) void gemv8_k(const float* __restrict__ X,
                                               const float* __restrict__ W,
                                               float* __restrict__ out, int N) {
    __shared__ float xs[BB][RPB];
    const int tid  = threadIdx.x;
    const int col  = blockIdx.x * 512 + tid * 2;
    const int row0 = blockIdx.y * RPB;
    for (int idx = tid; idx < BB * RPB; idx += 256) {
        int b = idx / RPB, r = idx - b * RPB;
        xs[b][r] = X[b * N + row0 + r];
    }
    __syncthreads();
    float acc[BB][2] = {};
    const float* Wp = W + (size_t)row0 * M + col;
    for (int r = 0; r < RPB; r += 4) {
        float2 w0 = *(const float2*)(Wp);
        float2 w1 = *(const float2*)(Wp + M);
        float2 w2 = *(const float2*)(Wp + 2 * (size_t)M);
        float2 w3 = *(const float2*)(Wp + 3 * (size_t)M);
        Wp += 4 * (size_t)M;
        #pragma unroll
        for (int b = 0; b < BB; ++b) {
            float4 xv = *(const float4*)&xs[b][r];
            acc[b][0] += xv.x*w0.x + xv.y*w1.x + xv.z*w2.x + xv.w*w3.x;
            acc[b][1] += xv.x*w0.y + xv.y*w1.y + xv.z*w2.y + xv.w*w3.y;
        }
    }
    #pragma unroll
    for (int b = 0; b < BB; ++b) {
        atomicAdd(&out[b * M + col],     acc[b][0]);
        atomicAdd(&out[b * M + col + 1], acc[b][1]);
    }
}

// dual GEMV (mlp_w1 & mlp_w3 share the activation reads)
template<int RPB, int M>
__global__ __launch_bounds__(256) void gemv8_dual_k(const float* __restrict__ X,
                                                    const float* __restrict__ W1,
                                                    const float* __restrict__ W3,
                                                    float* __restrict__ o1,
                                                    float* __restrict__ o3, int N) {
    __shared__ float xs[BB][RPB];
    const int tid  = threadIdx.x;
    const int col  = blockIdx.x * 512 + tid * 2;
    const int row0 = blockIdx.y * RPB;
    for (int idx = tid; idx < BB * RPB; idx += 256) {
        int b = idx / RPB, r = idx - b * RPB;
        xs[b][r] = X[b * N + row0 + r];
    }
    __syncthreads();
    float acc1[BB][2] = {};
    float acc3[BB][2] = {};
    const float* W1p = W1 + (size_t)row0 * M + col;
    const float* W3p = W3 + (size_t)row0 * M + col;
    for (int r = 0; r < RPB; r += 2) {
        float2 a0 = *(const float2*)(W1p);
        float2 a1 = *(const float2*)(W1p + M);
        float2 b0 = *(const float2*)(W3p);
        float2 b1 = *(const float2*)(W3p + M);
        W1p += 2 * (size_t)M;
        W3p += 2 * (size_t)M;
        #pragma unroll
        for (int b = 0; b < BB; ++b) {
            float2 xv = *(const float2*)&xs[b][r];
            acc1[b][0] += xv.x*a0.x + xv.y*a1.x;
            acc1[b][1] += xv.x*a0.y + xv.y*a1.y;
            acc3[b][0] += xv.x*b0.x + xv.y*b1.x;
            acc3[b][1] += xv.x*b0.y + xv.y*b1.y;
        }
    }
    #pragma unroll
    for (int b = 0; b < BB; ++b) {
        atomicAdd(&o1[b * M + col],     acc1[b][0]);
        atomicAdd(&o1[b * M + col + 1], acc1[b][1]);
        atomicAdd(&o3[b * M + col],     acc3[b][0]);
        atomicAdd(&o3[b * M + col + 1], acc3[b][1]);
    }
}

// ---------------- FIR + gating + IIR ----------------
__global__ __launch_bounds__(256) void fir_iir_k(const float* __restrict__ z,
                                                 const float* __restrict__ fir_state,
                                                 const float* __restrict__ iir_state,
                                                 const float* __restrict__ sf_weight,
                                                 const float* __restrict__ sf_bias,
                                                 const float* __restrict__ D_res,
                                                 const float* __restrict__ residues,
                                                 const float* __restrict__ log_poles,
                                                 float* __restrict__ new_fir,
                                                 float* __restrict__ new_iir,
                                                 float* __restrict__ y) {
    const int i = blockIdx.x * 256 + threadIdx.x;   // [0, B*D)
    const int b = i >> 12;          // /4096
    const int d = i & (DD - 1);
    const int h = d >> 7;           // /128
    const int p = d & (DPH - 1);
    const int j0 = h * (3 * DPH) + p;
    float zp[3];
    #pragma unroll
    for (int k = 0; k < 3; ++k) {
        int j = j0 + k * DPH;
        float u  = z[b * D3 + j];
        float f0 = fir_state[(b * D3 + j) * 2 + 0];
        float f1 = fir_state[(b * D3 + j) * 2 + 1];
        zp[k] = sf_weight[j*3+2] * u + f0 * sf_weight[j*3+0] + f1 * sf_weight[j*3+1] + sf_bias[j];
        new_fir[(b * D3 + j) * 2 + 0] = f1;
        new_fir[(b * D3 + j) * 2 + 1] = u;
    }
    float x2 = zp[0], x1 = zp[1], v = zp[2];
    float x1v = x1 * v;
    float res = 0.f;
    #pragma unroll
    for (int s = 0; s < SS; ++s) {
        float pole = expf(log_poles[d * SS + s]);
        float ni = pole * iir_state[(b * DD + d) * SS + s] + x1v;
        new_iir[(b * DD + d) * SS + s] = ni;
        res += residues[d * SS + s] * ni;
    }
    y[b * DD + d] = x2 * (res + D_res[d] * x1v);
}

// ---------------- post-attn residual + rmsnorm ----------------
__global__ __launch_bounds__(256) void post_k(const float* __restrict__ xw,
                                              const float* __restrict__ out_b,
                                              const float* __restrict__ x,
                                              const float* __restrict__ w,
                                              float* __restrict__ xattn,
                                              float* __restrict__ xn2) {
    const int b = blockIdx.x;
    const int tid = threadIdx.x;
    float ss = 0.f;
    for (int d = tid; d < DD; d += 256) {
        float v = xw[b*DD + d] + out_b[d] + x[b*DD + d];
        xattn[b*DD + d] = v;
        ss += v*v;
    }
    __shared__ float red[4];
    #pragma unroll
    for (int o = 32; o > 0; o >>= 1) ss += __shfl_down(ss, o);
    if ((tid & 63) == 0) red[tid >> 6] = ss;
    __syncthreads();
    float total = red[0] + red[1] + red[2] + red[3];
    float scale = rsqrtf(total / (float)DD + 1e-6f);
    for (int d = tid; d < DD; d += 256) xn2[b*DD + d] = xattn[b*DD + d] * scale * w[d];
}

// ---------------- silu gate ----------------
__global__ __launch_bounds__(256) void gate_k(const float* __restrict__ a1,
                                              const float* __restrict__ a3,
                                              float* __restrict__ g) {
    const int i = blockIdx.x * 256 + threadIdx.x;
    float v = a1[i];
    float s = v / (1.f + expf(-v));
    g[i] = s * a3[i];
}

// ---------------- final residual ----------------
__global__ __launch_bounds__(256) void final_k(const float* __restrict__ xd,
                                               const float* __restrict__ xattn,
                                               float* __restrict__ out) {
    const int i = blockIdx.x * 256 + threadIdx.x;
    out[i] = xd[i] + xattn[i];
}

extern "C" void kernel_launch(void* const* d_in, const int* in_sizes, int n_in,
                              void* d_out, int out_size, void* d_ws, size_t ws_size,
                              hipStream_t stream) {
    const float* x         = (const float*)d_in[0];
    const float* fir_state = (const float*)d_in[1];
    const float* iir_state = (const float*)d_in[2];
    const float* pre_w     = (const float*)d_in[3];
    const float* proj_w    = (const float*)d_in[4];
    const float* sf_weight = (const float*)d_in[5];
    const float* sf_bias   = (const float*)d_in[6];
    const float* D_res     = (const float*)d_in[7];
    const float* residues  = (const float*)d_in[8];
    const float* log_poles = (const float*)d_in[9];
    const float* out_w     = (const float*)d_in[10];
    const float* out_b     = (const float*)d_in[11];
    const float* post_w    = (const float*)d_in[12];
    const float* mlp_w1    = (const float*)d_in[13];
    const float* mlp_w3    = (const float*)d_in[14];
    const float* mlp_w2    = (const float*)d_in[15];

    float* ws = (float*)d_ws;
    float* z     = ws + WS_Z;
    float* xw    = ws + WS_XW;
    float* a1    = ws + WS_A1;
    float* a3    = ws + WS_A3;
    float* xd    = ws + WS_XD;
    float* xn1   = ws + WS_XN1;
    float* y     = ws + WS_Y;
    float* xattn = ws + WS_XATTN;
    float* xn2   = ws + WS_XN2;
    float* g     = ws + WS_G;

    float* out_x   = (float*)d_out;               // [B][1][D]   32768
    float* new_fir = out_x + BB * DD;             // [B][3D][2]  196608
    float* new_iir = new_fir + BB * D3 * 2;       // [B][D][S]   524288

    // zero the atomic-accumulation region
    hipMemsetAsync(ws, 0, (size_t)WS_ZERO_COUNT * sizeof(float), stream);

    // 1. pre-rmsnorm
    rmsnorm1_k<<<BB, 256, 0, stream>>>(x, pre_w, xn1);

    // 2. z = xn1 @ proj_w   (4096 x 12288)
    gemv8_k<256, D3><<<dim3(D3/512, DD/256), 256, 0, stream>>>(xn1, proj_w, z, DD);

    // 3. FIR/IIR/gating; writes new_fir, new_iir (outputs) and y
    fir_iir_k<<<(BB*DD)/256, 256, 0, stream>>>(z, fir_state, iir_state, sf_weight,
                                               sf_bias, D_res, residues, log_poles,
                                               new_fir, new_iir, y);

    // 4. xw = y @ out_w     (4096 x 4096)
    gemv8_k<128, DD><<<dim3(DD/512, DD/128), 256, 0, stream>>>(y, out_w, xw, DD);

    // 5. xattn = xw + out_b + x ; xn2 = rmsnorm(xattn, post_w)
    post_k<<<BB, 256, 0, stream>>>(xw, out_b, x, post_w, xattn, xn2);

    // 6. a1 = xn2 @ mlp_w1, a3 = xn2 @ mlp_w3   (4096 x 16384, dual)
    gemv8_dual_k<256, FFF><<<dim3(FFF/512, DD/256), 256, 0, stream>>>(xn2, mlp_w1, mlp_w3,
                                                                      a1, a3, DD);

    // 7. g = silu(a1) * a3
    gate_k<<<(BB*FFF)/256, 256, 0, stream>>>(a1, a3, g);

    // 8. xd = g @ mlp_w2    (16384 x 4096)
    gemv8_k<512, DD><<<dim3(DD/512, FFF/512), 256, 0, stream>>>(g, mlp_w2, xd, FFF);

    // 9. x_out = xattn + xd
    final_k<<<(BB*DD)/256, 256, 0, stream>>>(xd, xattn, out_x);
}